// Round 1
// 1439.932 us; speedup vs baseline: 1.3723x; 1.3723x over previous
//
#include <hip/hip_runtime.h>

#define BB 32
#define NN 2048
#define MM 512
#define DD 512
#define TS 64
#define KC 16
#define PAD 4  // LDS row stride 68 floats for the fp32 kernels

typedef _Float16 half4f __attribute__((ext_vector_type(4)));
typedef _Float16 half8f __attribute__((ext_vector_type(8)));
typedef float    f32x16 __attribute__((ext_vector_type(16)));

// K1: c1[b,n] = C[b,n,:]·w1 ; q2[b,m] = Q[b,m,:]·w2. One wave per row, 4 waves/block.
__global__ __launch_bounds__(256) void k_dots(const float* __restrict__ C, const float* __restrict__ Q,
                                              const float* __restrict__ w,
                                              float* __restrict__ c1, float* __restrict__ q2) {
    int wid  = blockIdx.x * 4 + (threadIdx.x >> 6);
    int lane = threadIdx.x & 63;
    const int NR1 = BB * NN;
    const float* src; const float* wv; float* dst;
    if (wid < NR1) { src = C + (size_t)wid * DD; wv = w;       dst = c1 + wid; }
    else { int r = wid - NR1; src = Q + (size_t)r * DD; wv = w + DD; dst = q2 + r; }
    float4 a0 = *(const float4*)(src + lane * 8);
    float4 a1 = *(const float4*)(src + lane * 8 + 4);
    float4 b0 = *(const float4*)(wv  + lane * 8);
    float4 b1 = *(const float4*)(wv  + lane * 8 + 4);
    float s = a0.x * b0.x + a0.y * b0.y + a0.z * b0.z + a0.w * b0.w
            + a1.x * b1.x + a1.y * b1.y + a1.z * b1.z + a1.w * b1.w;
#pragma unroll
    for (int o = 32; o > 0; o >>= 1) s += __shfl_down(s, o);
    if (lane == 0) *dst = s;
}

// K1b: Qt[b,d,m] = fp16(Q[b,m,d]) with Qmask-masked m-rows zeroed (mask folded into the
// MFMA B-operand so E can stay unmasked as the shared A-operand in k_AB).
__global__ __launch_bounds__(256) void k_qt(const float* __restrict__ Q, const int* __restrict__ Qmask,
                                            _Float16* __restrict__ Qt) {
    __shared__ float Ls[64][65];
    const int bid = blockIdx.x;
    const int b   = bid >> 6;
    const int rem = bid & 63;
    const int m0  = (rem >> 3) << 6;
    const int d0  = (rem & 7) << 6;
    const int tid = threadIdx.x;
    const int r   = tid >> 4;          // 0..15
    const int c4  = (tid & 15) << 2;   // 0..60 step 4
#pragma unroll
    for (int p = 0; p < 4; ++p) {
        float4 v = *(const float4*)(Q + ((size_t)(b * MM + m0 + r + p * 16)) * DD + d0 + c4);
        const int m = r + p * 16;
        Ls[c4 + 0][m] = v.x; Ls[c4 + 1][m] = v.y; Ls[c4 + 2][m] = v.z; Ls[c4 + 3][m] = v.w;
    }
    __syncthreads();
    float z[4];
#pragma unroll
    for (int i = 0; i < 4; ++i) z[i] = Qmask[b * MM + m0 + c4 + i] ? 0.f : 1.f;
#pragma unroll
    for (int p = 0; p < 4; ++p) {
        const int d = r + p * 16;
        half4f o;
#pragma unroll
        for (int i = 0; i < 4; ++i) o[i] = (_Float16)(Ls[d][c4 + i] * z[i]);
        *(half4f*)&Qt[((size_t)(b * DD + d0 + d)) * MM + m0 + c4] = o;
    }
}

// K2: E[b,n,m] = fp16(exp(c1 + q2 + (C*w3)·Q)); masked row/col sums of the QUANTIZED exp
// accumulated to rsum/csum (fp32) via LDS + global atomics.
__global__ __launch_bounds__(256) void k_sgemm(const float* __restrict__ C, const float* __restrict__ Q,
                                               const float* __restrict__ w,
                                               const int* __restrict__ Cmask, const int* __restrict__ Qmask,
                                               const float* __restrict__ c1, const float* __restrict__ q2,
                                               _Float16* __restrict__ E, float* __restrict__ rsum,
                                               float* __restrict__ csum) {
    __shared__ float As[KC][TS + PAD];  // As[k][n]  (C*w3)
    __shared__ float Bs[KC][TS + PAD];  // Bs[k][m]  (Q)
    __shared__ float rowp[TS], colp[TS];
    const int bid = blockIdx.x;
    const int b   = bid >> 8;
    const int rem = bid & 255;
    const int n0  = (rem >> 3) << 6;
    const int m0  = (rem & 7) << 6;
    const int tid = threadIdx.x;
    const int tx = tid & 15, ty = tid >> 4;
    const int lr = tid >> 2, lk4 = (tid & 3) << 2;
    if (tid < TS) { rowp[tid] = 0.f; colp[tid] = 0.f; }
    float acc[4][4] = {};
    const float* Cb = C + ((size_t)(b * NN + n0)) * DD;
    const float* Qb = Q + ((size_t)(b * MM + m0)) * DD;
    const float* w3 = w + 2 * DD;
    for (int k0 = 0; k0 < DD; k0 += KC) {
        float4 cv = *(const float4*)(Cb + (size_t)lr * DD + k0 + lk4);
        float4 qv = *(const float4*)(Qb + (size_t)lr * DD + k0 + lk4);
        float4 wv = *(const float4*)(w3 + k0 + lk4);
        __syncthreads();
        As[lk4 + 0][lr] = cv.x * wv.x;
        As[lk4 + 1][lr] = cv.y * wv.y;
        As[lk4 + 2][lr] = cv.z * wv.z;
        As[lk4 + 3][lr] = cv.w * wv.w;
        Bs[lk4 + 0][lr] = qv.x;
        Bs[lk4 + 1][lr] = qv.y;
        Bs[lk4 + 2][lr] = qv.z;
        Bs[lk4 + 3][lr] = qv.w;
        __syncthreads();
#pragma unroll
        for (int kk = 0; kk < KC; ++kk) {
            const float4 av = *(const float4*)&As[kk][ty << 2];
            const float4 bv = *(const float4*)&Bs[kk][tx << 2];
            const float a_[4] = {av.x, av.y, av.z, av.w};
            const float b_[4] = {bv.x, bv.y, bv.z, bv.w};
#pragma unroll
            for (int i = 0; i < 4; ++i)
#pragma unroll
                for (int j = 0; j < 4; ++j) acc[i][j] += a_[i] * b_[j];
        }
    }
    const int gn = b * NN + n0;
    const int gm = b * MM + m0;
    float c1v[4], q2v[4]; int cmv[4], qmv[4];
#pragma unroll
    for (int i = 0; i < 4; ++i) { c1v[i] = c1[gn + (ty << 2) + i]; cmv[i] = Cmask[gn + (ty << 2) + i]; }
#pragma unroll
    for (int j = 0; j < 4; ++j) { q2v[j] = q2[gm + (tx << 2) + j]; qmv[j] = Qmask[gm + (tx << 2) + j]; }
    float rp[4] = {0, 0, 0, 0}, cp[4] = {0, 0, 0, 0};
#pragma unroll
    for (int i = 0; i < 4; ++i) {
        half4f ev;
#pragma unroll
        for (int j = 0; j < 4; ++j) {
            float e = __expf(acc[i][j] + c1v[i] + q2v[j]);
            _Float16 eh = (_Float16)e;  // fp16 never overflows here: |S| <~ 8 -> e^S < 3e3
            float eq = (float)eh;
            ev[j] = eh;
            rp[i] += qmv[j] ? 0.f : eq;
            cp[j] += cmv[i] ? 0.f : eq;
        }
        *(half4f*)&E[((size_t)(gn + (ty << 2) + i)) * MM + m0 + (tx << 2)] = ev;
    }
#pragma unroll
    for (int i = 0; i < 4; ++i) atomicAdd(&rowp[(ty << 2) + i], rp[i]);
#pragma unroll
    for (int j = 0; j < 4; ++j) atomicAdd(&colp[(tx << 2) + j], cp[j]);
    __syncthreads();
    if (tid < TS) atomicAdd(&rsum[gn + tid], rowp[tid]);
    else if (tid < 2 * TS) atomicAdd(&csum[gm + tid - TS], colp[tid - TS]);
}

// K3: Tt[b,d,m] = fp16( sum_n (Cmask[n]?0:E[n,m]) * C[b,n,d] / csum[b,m] ), stored TRANSPOSED
// ([d][m], m-contiguous) so it serves directly as an MFMA B-operand in k_AB; Qmask-masked
// m-rows zeroed here (mask folded off E).
__global__ __launch_bounds__(256) void k_T(const _Float16* __restrict__ E, const float* __restrict__ C,
                                           const int* __restrict__ Cmask, const int* __restrict__ Qmask,
                                           const float* __restrict__ csum,
                                           _Float16* __restrict__ Tt) {
    __shared__ float Ws[KC][TS + PAD];  // Ws[k(n)][m]
    __shared__ float Cs[KC][TS + PAD];  // Cs[k(n)][d]
    const int bid = blockIdx.x;
    const int b   = bid >> 6;
    const int rem = bid & 63;
    const int m0  = (rem >> 3) << 6;
    const int d0  = (rem & 7) << 6;
    const int tid = threadIdx.x;
    const int tx = tid & 15, ty = tid >> 4;
    const int kk = tid >> 4, c4 = (tid & 15) << 2;
    float acc[4][4] = {};
    for (int n0 = 0; n0 < NN; n0 += KC) {
        const int n = n0 + kk;
        half4f ev = *(const half4f*)&E[((size_t)(b * NN + n)) * MM + m0 + c4];
        float4  cv = *(const float4*)(C + ((size_t)(b * NN + n)) * DD + d0 + c4);
        const float z = Cmask[b * NN + n] ? 0.f : 1.f;
        __syncthreads();
        *(float4*)&Ws[kk][c4] = make_float4((float)ev[0] * z, (float)ev[1] * z,
                                            (float)ev[2] * z, (float)ev[3] * z);
        *(float4*)&Cs[kk][c4] = cv;
        __syncthreads();
#pragma unroll
        for (int k2 = 0; k2 < KC; ++k2) {
            const float4 av = *(const float4*)&Ws[k2][ty << 2];
            const float4 bv = *(const float4*)&Cs[k2][tx << 2];
            const float a_[4] = {av.x, av.y, av.z, av.w};
            const float b_[4] = {bv.x, bv.y, bv.z, bv.w};
#pragma unroll
            for (int i = 0; i < 4; ++i)
#pragma unroll
                for (int j = 0; j < 4; ++j) acc[i][j] += a_[i] * b_[j];
        }
    }
    float inv[4], qz[4];
#pragma unroll
    for (int i = 0; i < 4; ++i) {
        const int m = m0 + (ty << 2) + i;
        inv[i] = 1.f / csum[b * MM + m];
        qz[i]  = Qmask[b * MM + m] ? 0.f : 1.f;
    }
#pragma unroll
    for (int j = 0; j < 4; ++j) {
        half4f ov;
#pragma unroll
        for (int i = 0; i < 4; ++i) ov[i] = (_Float16)(acc[i][j] * inv[i] * qz[i]);
        *(half4f*)&Tt[((size_t)(b * DD + d0 + (tx << 2) + j)) * MM + m0 + (ty << 2)] = ov;
    }
}

// K4 (MFMA): A[b,n,d] = (1/rsum[n]) * sum_m E[n,m]*Qt[d,m]; Bout likewise with Tt.
// 128(n) x 128(d) tile, 4 waves 2x2, 64x64 per wave, K-step 32 over m,
// v_mfma_f32_32x32x16_f16. E is the shared A-operand (Qmask folded into Qt/Tt).
// LDS rows padded to 40 halves (80 B) -> <=2-way bank aliasing on ds_read_b128 (free).
#define KS 32
#define LDK 40

__global__ __launch_bounds__(256, 2) void k_AB(const _Float16* __restrict__ E,
                                               const _Float16* __restrict__ Qt,
                                               const _Float16* __restrict__ Tt,
                                               const float* __restrict__ rsum,
                                               float* __restrict__ outA, float* __restrict__ outB) {
    __shared__ _Float16 Es[128 * LDK];
    __shared__ _Float16 Ws[2][128 * LDK];
    const int hw  = blockIdx.x;
    const int bid = ((hw & 7) << 8) | (hw >> 3);  // XCD-chunked swizzle (2048 = 8*256, bijective)
    const int b   = bid >> 6;
    const int rem = bid & 63;
    const int n0  = (rem >> 2) << 7;   // 16 n-blocks
    const int d0  = (rem & 3) << 7;    // 4 d-blocks (consecutive logical ids share the E panel)
    const int tid = threadIdx.x;
    const int lane = tid & 63;
    const int wid  = tid >> 6;
    const int wr = wid >> 1, wc = wid & 1;
    // staging: thread -> (row = tid>>2 and +64, 16B segment = tid&3) of each 128x32 tile
    const int srow = tid >> 2;
    const int scol = (tid & 3) << 3;
    const _Float16* g0 = E  + ((size_t)(b * NN + n0 + srow)) * MM + scol;
    const _Float16* g1 = Qt + ((size_t)(b * DD + d0 + srow)) * MM + scol;
    const _Float16* g2 = Tt + ((size_t)(b * DD + d0 + srow)) * MM + scol;
    const int wofs = srow * LDK + scol;
    f32x16 accA[2][2] = {};
    f32x16 accB[2][2] = {};
    const int ar  = wr * 64 + (lane & 31);   // A-fragment row (n_local), +i*32
    const int bc  = wc * 64 + (lane & 31);   // B-fragment col (d_local), +j*32
    const int kof = (lane >> 5) << 3;        // per-lane k offset within 16-k fragment
    for (int k0 = 0; k0 < MM; k0 += KS) {
        half8f e0 = *(const half8f*)(g0 + k0);
        half8f e1 = *(const half8f*)(g0 + k0 + (size_t)64 * MM);
        half8f q0 = *(const half8f*)(g1 + k0);
        half8f q1 = *(const half8f*)(g1 + k0 + (size_t)64 * MM);
        half8f t0 = *(const half8f*)(g2 + k0);
        half8f t1 = *(const half8f*)(g2 + k0 + (size_t)64 * MM);
        __syncthreads();   // previous iteration's LDS reads done
        *(half8f*)&Es[wofs]                = e0;
        *(half8f*)&Es[wofs + 64 * LDK]     = e1;
        *(half8f*)&Ws[0][wofs]             = q0;
        *(half8f*)&Ws[0][wofs + 64 * LDK]  = q1;
        *(half8f*)&Ws[1][wofs]             = t0;
        *(half8f*)&Ws[1][wofs + 64 * LDK]  = t1;
        __syncthreads();   // tile visible
#pragma unroll
        for (int h = 0; h < 2; ++h) {
            const int ko = (h << 4) + kof;
            half8f a0  = *(const half8f*)&Es[ar * LDK + ko];
            half8f a1  = *(const half8f*)&Es[(ar + 32) * LDK + ko];
            half8f bq0 = *(const half8f*)&Ws[0][bc * LDK + ko];
            half8f bq1 = *(const half8f*)&Ws[0][(bc + 32) * LDK + ko];
            half8f bt0 = *(const half8f*)&Ws[1][bc * LDK + ko];
            half8f bt1 = *(const half8f*)&Ws[1][(bc + 32) * LDK + ko];
            accA[0][0] = __builtin_amdgcn_mfma_f32_32x32x16_f16(a0, bq0, accA[0][0], 0, 0, 0);
            accA[0][1] = __builtin_amdgcn_mfma_f32_32x32x16_f16(a0, bq1, accA[0][1], 0, 0, 0);
            accA[1][0] = __builtin_amdgcn_mfma_f32_32x32x16_f16(a1, bq0, accA[1][0], 0, 0, 0);
            accA[1][1] = __builtin_amdgcn_mfma_f32_32x32x16_f16(a1, bq1, accA[1][1], 0, 0, 0);
            accB[0][0] = __builtin_amdgcn_mfma_f32_32x32x16_f16(a0, bt0, accB[0][0], 0, 0, 0);
            accB[0][1] = __builtin_amdgcn_mfma_f32_32x32x16_f16(a0, bt1, accB[0][1], 0, 0, 0);
            accB[1][0] = __builtin_amdgcn_mfma_f32_32x32x16_f16(a1, bt0, accB[1][0], 0, 0, 0);
            accB[1][1] = __builtin_amdgcn_mfma_f32_32x32x16_f16(a1, bt1, accB[1][1], 0, 0, 0);
        }
    }
    // epilogue: C/D layout col=lane&31, row=(reg&3)+8*(reg>>2)+4*(lane>>5) [m74/m101-verified]
    const int dc = d0 + wc * 64 + (lane & 31);
#pragma unroll
    for (int i = 0; i < 2; ++i) {
#pragma unroll
        for (int r = 0; r < 16; ++r) {
            const int row = (r & 3) + ((r >> 2) << 3) + ((lane >> 5) << 2);
            const int n = n0 + wr * 64 + i * 32 + row;
            const float inv = __builtin_amdgcn_rcpf(rsum[b * NN + n]);
            const size_t o = ((size_t)(b * NN + n)) * DD + dc;
            outA[o]      = accA[i][0][r] * inv;
            outA[o + 32] = accA[i][1][r] * inv;
            outB[o]      = accB[i][0][r] * inv;
            outB[o + 32] = accB[i][1][r] * inv;
        }
    }
}

extern "C" void kernel_launch(void* const* d_in, const int* in_sizes, int n_in,
                              void* d_out, int out_size, void* d_ws, size_t ws_size,
                              hipStream_t stream) {
    const float* C = (const float*)d_in[0];
    const float* Q = (const float*)d_in[1];
    const int* Cmask = (const int*)d_in[2];
    const int* Qmask = (const int*)d_in[3];
    const float* w  = (const float*)d_in[4];

    const size_t BNM = (size_t)BB * NN * MM;   // 33.5M (E, fp16)
    const size_t BMD = (size_t)BB * MM * DD;   // 8.4M  (Tt/Qt, fp16, [b][d][m])
    const size_t BN  = (size_t)BB * NN;
    const size_t BM  = (size_t)BB * MM;

    _Float16* E  = (_Float16*)d_ws;
    _Float16* Tt = E + BNM;
    _Float16* Qt = Tt + BMD;
    float* fbase = (float*)(Qt + BMD);         // byte offset 100,663,296 — 16B aligned
    float* c1   = fbase;
    float* q2   = c1 + BN;
    float* rsum = q2 + BM;
    float* csum = rsum + BN;

    hipMemsetAsync(rsum, 0, (BN + BM) * sizeof(float), stream);

    k_dots<<<(int)((BN + BM) / 4), 256, 0, stream>>>(C, Q, w, c1, q2);
    k_qt<<<BB * 64, 256, 0, stream>>>(Q, Qmask, Qt);
    k_sgemm<<<BB * (NN / TS) * (MM / TS), 256, 0, stream>>>(C, Q, w, Cmask, Qmask, c1, q2, E, rsum, csum);
    k_T<<<BB * (MM / TS) * (DD / TS), 256, 0, stream>>>(E, C, Cmask, Qmask, csum, Tt);
    k_AB<<<2048, 256, 0, stream>>>(E, Qt, Tt, rsum,
                                   (float*)d_out, (float*)d_out + (size_t)BB * NN * DD);
}

// Round 2
// 755.699 us; speedup vs baseline: 2.6147x; 1.9054x over previous
//
#include <hip/hip_runtime.h>

#define BB 32
#define NN 2048
#define MM 512
#define DD 512
#define TS 64
#define KC 16
#define PAD 4
#define LDKH 40   // halves per LDS row in MFMA kernels: 80 B rows, 16B-aligned, 4-way max alias

typedef _Float16 half4f __attribute__((ext_vector_type(4)));
typedef _Float16 half8f __attribute__((ext_vector_type(8)));
typedef float    f32x16 __attribute__((ext_vector_type(16)));

// K1: c1[b,n] = C[b,n,:]·w1 ; q2[b,m] = Q[b,m,:]·w2. One wave per row, 4 waves/block.
__global__ __launch_bounds__(256) void k_dots(const float* __restrict__ C, const float* __restrict__ Q,
                                              const float* __restrict__ w,
                                              float* __restrict__ c1, float* __restrict__ q2) {
    int wid  = blockIdx.x * 4 + (threadIdx.x >> 6);
    int lane = threadIdx.x & 63;
    const int NR1 = BB * NN;
    const float* src; const float* wv; float* dst;
    if (wid < NR1) { src = C + (size_t)wid * DD; wv = w;       dst = c1 + wid; }
    else { int r = wid - NR1; src = Q + (size_t)r * DD; wv = w + DD; dst = q2 + r; }
    float4 a0 = *(const float4*)(src + lane * 8);
    float4 a1 = *(const float4*)(src + lane * 8 + 4);
    float4 b0 = *(const float4*)(wv  + lane * 8);
    float4 b1 = *(const float4*)(wv  + lane * 8 + 4);
    float s = a0.x * b0.x + a0.y * b0.y + a0.z * b0.z + a0.w * b0.w
            + a1.x * b1.x + a1.y * b1.y + a1.z * b1.z + a1.w * b1.w;
#pragma unroll
    for (int o = 32; o > 0; o >>= 1) s += __shfl_down(s, o);
    if (lane == 0) *dst = s;
}

// K1b: Qt[b,d,m] = fp16(Q[b,m,d]) with Qmask-masked m-rows zeroed.
__global__ __launch_bounds__(256) void k_qt(const float* __restrict__ Q, const int* __restrict__ Qmask,
                                            _Float16* __restrict__ Qt) {
    __shared__ float Ls[64][65];
    const int bid = blockIdx.x;
    const int b   = bid >> 6;
    const int rem = bid & 63;
    const int m0  = (rem >> 3) << 6;
    const int d0  = (rem & 7) << 6;
    const int tid = threadIdx.x;
    const int r   = tid >> 4;
    const int c4  = (tid & 15) << 2;
#pragma unroll
    for (int p = 0; p < 4; ++p) {
        float4 v = *(const float4*)(Q + ((size_t)(b * MM + m0 + r + p * 16)) * DD + d0 + c4);
        const int m = r + p * 16;
        Ls[c4 + 0][m] = v.x; Ls[c4 + 1][m] = v.y; Ls[c4 + 2][m] = v.z; Ls[c4 + 3][m] = v.w;
    }
    __syncthreads();
    float z[4];
#pragma unroll
    for (int i = 0; i < 4; ++i) z[i] = Qmask[b * MM + m0 + c4 + i] ? 0.f : 1.f;
#pragma unroll
    for (int p = 0; p < 4; ++p) {
        const int d = r + p * 16;
        half4f o;
#pragma unroll
        for (int i = 0; i < 4; ++i) o[i] = (_Float16)(Ls[d][c4 + i] * z[i]);
        *(half4f*)&Qt[((size_t)(b * DD + d0 + d)) * MM + m0 + c4] = o;
    }
}

// K1c: Ct[b,d,n] = fp16(C[b,n,d])  (pre-transpose so k_T's A-operand is k(=n)-contiguous).
__global__ __launch_bounds__(256) void k_ct(const float* __restrict__ C, _Float16* __restrict__ Ct) {
    __shared__ float Ls[64][65];
    const int bid = blockIdx.x;             // BB * 32 * 8
    const int b   = bid >> 8;
    const int nn0 = ((bid >> 3) & 31) << 6;
    const int dd0 = (bid & 7) << 6;
    const int tid = threadIdx.x;
    const int r   = tid >> 4;
    const int c4  = (tid & 15) << 2;
#pragma unroll
    for (int p = 0; p < 4; ++p) {
        const int n = r + (p << 4);
        float4 v = *(const float4*)(C + ((size_t)(b * NN + nn0 + n)) * DD + dd0 + c4);
        Ls[c4 + 0][n] = v.x; Ls[c4 + 1][n] = v.y; Ls[c4 + 2][n] = v.z; Ls[c4 + 3][n] = v.w;
    }
    __syncthreads();
#pragma unroll
    for (int p = 0; p < 4; ++p) {
        const int d = r + (p << 4);
        half4f o;
#pragma unroll
        for (int i = 0; i < 4; ++i) o[i] = (_Float16)Ls[d][c4 + i];
        *(half4f*)&Ct[((size_t)(b * DD + dd0 + d)) * NN + nn0 + c4] = o;
    }
}

// K2b: Et[b,m,n] = E[b,n,m] with Cmask(n)-masked entries zeroed (k_T's B-operand).
__global__ __launch_bounds__(256) void k_te(const _Float16* __restrict__ E, const int* __restrict__ Cmask,
                                            _Float16* __restrict__ Et) {
    __shared__ float Ls[64][65];
    const int bid = blockIdx.x;             // BB * 32 * 8
    const int b   = bid >> 8;
    const int nn0 = ((bid >> 3) & 31) << 6;
    const int mm0 = (bid & 7) << 6;
    const int tid = threadIdx.x;
    const int r   = tid >> 4;
    const int c4  = (tid & 15) << 2;
#pragma unroll
    for (int p = 0; p < 4; ++p) {
        const int n = r + (p << 4);
        half4f v = *(const half4f*)&E[((size_t)(b * NN + nn0 + n)) * MM + mm0 + c4];
        const float z = Cmask[b * NN + nn0 + n] ? 0.f : 1.f;
        Ls[c4 + 0][n] = (float)v[0] * z; Ls[c4 + 1][n] = (float)v[1] * z;
        Ls[c4 + 2][n] = (float)v[2] * z; Ls[c4 + 3][n] = (float)v[3] * z;
    }
    __syncthreads();
#pragma unroll
    for (int p = 0; p < 4; ++p) {
        const int m = r + (p << 4);
        half4f o;
#pragma unroll
        for (int i = 0; i < 4; ++i) o[i] = (_Float16)Ls[m][c4 + i];
        *(half4f*)&Et[((size_t)(b * MM + mm0 + m)) * NN + nn0 + c4] = o;
    }
}

// K2 (MFMA): S = (C*w3)·Q^T via 2-term fp16 split (hi·hi + 2^-11(hi·lo'+lo'·hi), lo'=resid*2048).
// E[b,n,m] = fp16(exp(S + c1 + q2)); masked row/col sums of the QUANTIZED exp -> rsum/csum.
// 128x128 tile, 4 waves 2x2, 64x64/wave, K-step 32 over d.
__global__ __launch_bounds__(256, 2) void k_sgemm(const float* __restrict__ C, const float* __restrict__ Q,
                                                  const float* __restrict__ w,
                                                  const int* __restrict__ Cmask, const int* __restrict__ Qmask,
                                                  const float* __restrict__ c1, const float* __restrict__ q2,
                                                  _Float16* __restrict__ E, float* __restrict__ rsum,
                                                  float* __restrict__ csum) {
    __shared__ _Float16 Ah[128 * LDKH], Al[128 * LDKH], Bh[128 * LDKH], Bl[128 * LDKH];
    __shared__ float rowp[128], colp[128], cmz[128], qmz[128], c1s[128], q2s[128];
    const int hw  = blockIdx.x;
    const int bid = ((hw & 7) << 8) | (hw >> 3);   // XCD-chunked swizzle, 2048 = 8*256
    const int b   = bid >> 6;
    const int rem = bid & 63;
    const int n0  = (rem >> 2) << 7;   // 16 n-blocks
    const int m0  = (rem & 3) << 7;    // 4 m-blocks (consecutive logical ids share the C panel)
    const int tid = threadIdx.x;
    const int lane = tid & 63;
    const int wid  = tid >> 6;
    const int wr = wid >> 1, wc = wid & 1;
    const int srow = tid >> 3;          // 0..31
    const int sc4  = (tid & 7) << 2;    // 0..28
    if (tid < 128) {
        rowp[tid] = 0.f; colp[tid] = 0.f;
        cmz[tid] = Cmask[b * NN + n0 + tid] ? 0.f : 1.f;
        c1s[tid] = c1[b * NN + n0 + tid];
    } else {
        const int t = tid - 128;
        qmz[t] = Qmask[b * MM + m0 + t] ? 0.f : 1.f;
        q2s[t] = q2[b * MM + m0 + t];
    }
    f32x16 accH[2][2] = {};
    f32x16 accX[2][2] = {};
    const int ar  = wr * 64 + (lane & 31);
    const int bc  = wc * 64 + (lane & 31);
    const int kof = (lane >> 5) << 3;
    const float* Cb = C + ((size_t)(b * NN + n0)) * DD;
    const float* Qb = Q + ((size_t)(b * MM + m0)) * DD;
    const float* w3 = w + 2 * DD;
    for (int k0 = 0; k0 < DD; k0 += 32) {
        float4 wv = *(const float4*)(w3 + k0 + sc4);
        float4 ca[4], qa[4];
#pragma unroll
        for (int p = 0; p < 4; ++p) {
            ca[p] = *(const float4*)(Cb + (size_t)(srow + (p << 5)) * DD + k0 + sc4);
            qa[p] = *(const float4*)(Qb + (size_t)(srow + (p << 5)) * DD + k0 + sc4);
        }
        __syncthreads();
#pragma unroll
        for (int p = 0; p < 4; ++p) {
            const int ofs = (srow + (p << 5)) * LDKH + sc4;
            float ax[4] = {ca[p].x * wv.x, ca[p].y * wv.y, ca[p].z * wv.z, ca[p].w * wv.w};
            float bx[4] = {qa[p].x, qa[p].y, qa[p].z, qa[p].w};
            half4f ah, al, bh, bl;
#pragma unroll
            for (int e = 0; e < 4; ++e) {
                _Float16 h = (_Float16)ax[e]; ah[e] = h;
                al[e] = (_Float16)((ax[e] - (float)h) * 2048.f);
                _Float16 g = (_Float16)bx[e]; bh[e] = g;
                bl[e] = (_Float16)((bx[e] - (float)g) * 2048.f);
            }
            *(half4f*)&Ah[ofs] = ah; *(half4f*)&Al[ofs] = al;
            *(half4f*)&Bh[ofs] = bh; *(half4f*)&Bl[ofs] = bl;
        }
        __syncthreads();
#pragma unroll
        for (int h = 0; h < 2; ++h) {
            const int ko = (h << 4) + kof;
            half8f ah0 = *(const half8f*)&Ah[ar * LDKH + ko];
            half8f ah1 = *(const half8f*)&Ah[(ar + 32) * LDKH + ko];
            half8f al0 = *(const half8f*)&Al[ar * LDKH + ko];
            half8f al1 = *(const half8f*)&Al[(ar + 32) * LDKH + ko];
            half8f bh0 = *(const half8f*)&Bh[bc * LDKH + ko];
            half8f bh1 = *(const half8f*)&Bh[(bc + 32) * LDKH + ko];
            half8f bl0 = *(const half8f*)&Bl[bc * LDKH + ko];
            half8f bl1 = *(const half8f*)&Bl[(bc + 32) * LDKH + ko];
            accH[0][0] = __builtin_amdgcn_mfma_f32_32x32x16_f16(ah0, bh0, accH[0][0], 0, 0, 0);
            accH[0][1] = __builtin_amdgcn_mfma_f32_32x32x16_f16(ah0, bh1, accH[0][1], 0, 0, 0);
            accH[1][0] = __builtin_amdgcn_mfma_f32_32x32x16_f16(ah1, bh0, accH[1][0], 0, 0, 0);
            accH[1][1] = __builtin_amdgcn_mfma_f32_32x32x16_f16(ah1, bh1, accH[1][1], 0, 0, 0);
            accX[0][0] = __builtin_amdgcn_mfma_f32_32x32x16_f16(ah0, bl0, accX[0][0], 0, 0, 0);
            accX[0][0] = __builtin_amdgcn_mfma_f32_32x32x16_f16(al0, bh0, accX[0][0], 0, 0, 0);
            accX[0][1] = __builtin_amdgcn_mfma_f32_32x32x16_f16(ah0, bl1, accX[0][1], 0, 0, 0);
            accX[0][1] = __builtin_amdgcn_mfma_f32_32x32x16_f16(al0, bh1, accX[0][1], 0, 0, 0);
            accX[1][0] = __builtin_amdgcn_mfma_f32_32x32x16_f16(ah1, bl0, accX[1][0], 0, 0, 0);
            accX[1][0] = __builtin_amdgcn_mfma_f32_32x32x16_f16(al1, bh0, accX[1][0], 0, 0, 0);
            accX[1][1] = __builtin_amdgcn_mfma_f32_32x32x16_f16(ah1, bl1, accX[1][1], 0, 0, 0);
            accX[1][1] = __builtin_amdgcn_mfma_f32_32x32x16_f16(al1, bh1, accX[1][1], 0, 0, 0);
        }
    }
    // epilogue: C/D layout col=lane&31, row=(r&3)+8*(r>>2)+4*(lane>>5)
    const float inv2k = 4.8828125e-4f;  // 2^-11
    const int mcol0 = wc * 64 + (lane & 31);
    const float qz0 = qmz[mcol0], qz1 = qmz[mcol0 + 32];
    const float q2v0 = q2s[mcol0], q2v1 = q2s[mcol0 + 32];
    const int hi4 = (lane >> 5) << 2;
    float colacc0 = 0.f, colacc1 = 0.f;
#pragma unroll
    for (int i = 0; i < 2; ++i) {
#pragma unroll
        for (int r = 0; r < 16; ++r) {
            const int nloc = wr * 64 + i * 32 + (r & 3) + ((r >> 2) << 3) + hi4;
            const float base = c1s[nloc];
            float S0 = accH[i][0][r] + accX[i][0][r] * inv2k + base + q2v0;
            float S1 = accH[i][1][r] + accX[i][1][r] * inv2k + base + q2v1;
            float e0 = __expf(S0), e1 = __expf(S1);
            _Float16 h0 = (_Float16)e0, h1 = (_Float16)e1;
            float eq0 = (float)h0, eq1 = (float)h1;
            const size_t erow = ((size_t)(b * NN + n0 + nloc)) * MM + m0;
            E[erow + mcol0]      = h0;
            E[erow + mcol0 + 32] = h1;
            const float cz = cmz[nloc];
            colacc0 += eq0 * cz;
            colacc1 += eq1 * cz;
            float rv = eq0 * qz0 + eq1 * qz1;
            rv += __shfl_xor(rv, 1);  rv += __shfl_xor(rv, 2);
            rv += __shfl_xor(rv, 4);  rv += __shfl_xor(rv, 8);
            rv += __shfl_xor(rv, 16);
            if ((lane & 31) == 0) atomicAdd(&rowp[nloc], rv);
        }
    }
    atomicAdd(&colp[mcol0], colacc0);
    atomicAdd(&colp[mcol0 + 32], colacc1);
    __syncthreads();
    if (tid < 128) atomicAdd(&rsum[b * NN + n0 + tid], rowp[tid]);
    else atomicAdd(&csum[b * MM + m0 + tid - 128], colp[tid - 128]);
}

// K3 (MFMA): Tt[b,d,m] = fp16( (1/csum[m]) * qz[m] * sum_n Ct[d,n]*Et[m,n] ).
// 128(d) x 128(m) tile, K = N = 2048, K-step 32; same structure as k_AB.
__global__ __launch_bounds__(256, 2) void k_T(const _Float16* __restrict__ Ct,
                                              const _Float16* __restrict__ Et,
                                              const float* __restrict__ csum,
                                              const int* __restrict__ Qmask,
                                              _Float16* __restrict__ Tt) {
    __shared__ _Float16 As[128 * LDKH];
    __shared__ _Float16 Bs[128 * LDKH];
    const int hw  = blockIdx.x;              // 512
    const int bid = ((hw & 7) << 6) | (hw >> 3);   // 512 = 8*64, bijective
    const int b   = bid >> 4;
    const int rem = bid & 15;
    const int d0  = (rem >> 2) << 7;
    const int m0  = (rem & 3) << 7;
    const int tid = threadIdx.x;
    const int lane = tid & 63;
    const int wid  = tid >> 6;
    const int wr = wid >> 1, wc = wid & 1;
    const int srow = tid >> 2;
    const int scol = (tid & 3) << 3;
    const _Float16* g0 = Ct + ((size_t)(b * DD + d0 + srow)) * NN + scol;
    const _Float16* g1 = Et + ((size_t)(b * MM + m0 + srow)) * NN + scol;
    const int wofs = srow * LDKH + scol;
    f32x16 acc[2][2] = {};
    const int ar  = wr * 64 + (lane & 31);
    const int bc  = wc * 64 + (lane & 31);
    const int kof = (lane >> 5) << 3;
    for (int k0 = 0; k0 < NN; k0 += 32) {
        half8f a0v = *(const half8f*)(g0 + k0);
        half8f a1v = *(const half8f*)(g0 + k0 + (size_t)64 * NN);
        half8f b0v = *(const half8f*)(g1 + k0);
        half8f b1v = *(const half8f*)(g1 + k0 + (size_t)64 * NN);
        __syncthreads();
        *(half8f*)&As[wofs]             = a0v;
        *(half8f*)&As[wofs + 64 * LDKH] = a1v;
        *(half8f*)&Bs[wofs]             = b0v;
        *(half8f*)&Bs[wofs + 64 * LDKH] = b1v;
        __syncthreads();
#pragma unroll
        for (int h = 0; h < 2; ++h) {
            const int ko = (h << 4) + kof;
            half8f a0 = *(const half8f*)&As[ar * LDKH + ko];
            half8f a1 = *(const half8f*)&As[(ar + 32) * LDKH + ko];
            half8f b0 = *(const half8f*)&Bs[bc * LDKH + ko];
            half8f b1 = *(const half8f*)&Bs[(bc + 32) * LDKH + ko];
            acc[0][0] = __builtin_amdgcn_mfma_f32_32x32x16_f16(a0, b0, acc[0][0], 0, 0, 0);
            acc[0][1] = __builtin_amdgcn_mfma_f32_32x32x16_f16(a0, b1, acc[0][1], 0, 0, 0);
            acc[1][0] = __builtin_amdgcn_mfma_f32_32x32x16_f16(a1, b0, acc[1][0], 0, 0, 0);
            acc[1][1] = __builtin_amdgcn_mfma_f32_32x32x16_f16(a1, b1, acc[1][1], 0, 0, 0);
        }
    }
    const int mc0 = m0 + wc * 64 + (lane & 31);
    const float s0 = (Qmask[b * MM + mc0]      ? 0.f : 1.f) / csum[b * MM + mc0];
    const float s1 = (Qmask[b * MM + mc0 + 32] ? 0.f : 1.f) / csum[b * MM + mc0 + 32];
    const int hi4 = (lane >> 5) << 2;
#pragma unroll
    for (int i = 0; i < 2; ++i) {
#pragma unroll
        for (int r = 0; r < 16; ++r) {
            const int d = d0 + wr * 64 + i * 32 + (r & 3) + ((r >> 2) << 3) + hi4;
            const size_t o = ((size_t)(b * DD + d)) * MM + mc0;
            Tt[o]      = (_Float16)(acc[i][0][r] * s0);
            Tt[o + 32] = (_Float16)(acc[i][1][r] * s1);
        }
    }
}

// K4 (MFMA): A[b,n,d] = (1/rsum[n]) * sum_m E[n,m]*Qt[d,m]; Bout likewise with Tt.
#define KS 32

__global__ __launch_bounds__(256, 2) void k_AB(const _Float16* __restrict__ E,
                                               const _Float16* __restrict__ Qt,
                                               const _Float16* __restrict__ Tt,
                                               const float* __restrict__ rsum,
                                               float* __restrict__ outA, float* __restrict__ outB) {
    __shared__ _Float16 Es[128 * LDKH];
    __shared__ _Float16 Ws[2][128 * LDKH];
    const int hw  = blockIdx.x;
    const int bid = ((hw & 7) << 8) | (hw >> 3);
    const int b   = bid >> 6;
    const int rem = bid & 63;
    const int n0  = (rem >> 2) << 7;
    const int d0  = (rem & 3) << 7;
    const int tid = threadIdx.x;
    const int lane = tid & 63;
    const int wid  = tid >> 6;
    const int wr = wid >> 1, wc = wid & 1;
    const int srow = tid >> 2;
    const int scol = (tid & 3) << 3;
    const _Float16* g0 = E  + ((size_t)(b * NN + n0 + srow)) * MM + scol;
    const _Float16* g1 = Qt + ((size_t)(b * DD + d0 + srow)) * MM + scol;
    const _Float16* g2 = Tt + ((size_t)(b * DD + d0 + srow)) * MM + scol;
    const int wofs = srow * LDKH + scol;
    f32x16 accA[2][2] = {};
    f32x16 accB[2][2] = {};
    const int ar  = wr * 64 + (lane & 31);
    const int bc  = wc * 64 + (lane & 31);
    const int kof = (lane >> 5) << 3;
    for (int k0 = 0; k0 < MM; k0 += KS) {
        half8f e0 = *(const half8f*)(g0 + k0);
        half8f e1 = *(const half8f*)(g0 + k0 + (size_t)64 * MM);
        half8f q0 = *(const half8f*)(g1 + k0);
        half8f q1 = *(const half8f*)(g1 + k0 + (size_t)64 * MM);
        half8f t0 = *(const half8f*)(g2 + k0);
        half8f t1 = *(const half8f*)(g2 + k0 + (size_t)64 * MM);
        __syncthreads();
        *(half8f*)&Es[wofs]                = e0;
        *(half8f*)&Es[wofs + 64 * LDKH]    = e1;
        *(half8f*)&Ws[0][wofs]             = q0;
        *(half8f*)&Ws[0][wofs + 64 * LDKH] = q1;
        *(half8f*)&Ws[1][wofs]             = t0;
        *(half8f*)&Ws[1][wofs + 64 * LDKH] = t1;
        __syncthreads();
#pragma unroll
        for (int h = 0; h < 2; ++h) {
            const int ko = (h << 4) + kof;
            half8f a0  = *(const half8f*)&Es[ar * LDKH + ko];
            half8f a1  = *(const half8f*)&Es[(ar + 32) * LDKH + ko];
            half8f bq0 = *(const half8f*)&Ws[0][bc * LDKH + ko];
            half8f bq1 = *(const half8f*)&Ws[0][(bc + 32) * LDKH + ko];
            half8f bt0 = *(const half8f*)&Ws[1][bc * LDKH + ko];
            half8f bt1 = *(const half8f*)&Ws[1][(bc + 32) * LDKH + ko];
            accA[0][0] = __builtin_amdgcn_mfma_f32_32x32x16_f16(a0, bq0, accA[0][0], 0, 0, 0);
            accA[0][1] = __builtin_amdgcn_mfma_f32_32x32x16_f16(a0, bq1, accA[0][1], 0, 0, 0);
            accA[1][0] = __builtin_amdgcn_mfma_f32_32x32x16_f16(a1, bq0, accA[1][0], 0, 0, 0);
            accA[1][1] = __builtin_amdgcn_mfma_f32_32x32x16_f16(a1, bq1, accA[1][1], 0, 0, 0);
            accB[0][0] = __builtin_amdgcn_mfma_f32_32x32x16_f16(a0, bt0, accB[0][0], 0, 0, 0);
            accB[0][1] = __builtin_amdgcn_mfma_f32_32x32x16_f16(a0, bt1, accB[0][1], 0, 0, 0);
            accB[1][0] = __builtin_amdgcn_mfma_f32_32x32x16_f16(a1, bt0, accB[1][0], 0, 0, 0);
            accB[1][1] = __builtin_amdgcn_mfma_f32_32x32x16_f16(a1, bt1, accB[1][1], 0, 0, 0);
        }
    }
    const int dc = d0 + wc * 64 + (lane & 31);
#pragma unroll
    for (int i = 0; i < 2; ++i) {
#pragma unroll
        for (int r = 0; r < 16; ++r) {
            const int row = (r & 3) + ((r >> 2) << 3) + ((lane >> 5) << 2);
            const int n = n0 + wr * 64 + i * 32 + row;
            const float inv = __builtin_amdgcn_rcpf(rsum[b * NN + n]);
            const size_t o = ((size_t)(b * NN + n)) * DD + dc;
            outA[o]      = accA[i][0][r] * inv;
            outA[o + 32] = accA[i][1][r] * inv;
            outB[o]      = accB[i][0][r] * inv;
            outB[o + 32] = accB[i][1][r] * inv;
        }
    }
}

extern "C" void kernel_launch(void* const* d_in, const int* in_sizes, int n_in,
                              void* d_out, int out_size, void* d_ws, size_t ws_size,
                              hipStream_t stream) {
    const float* C = (const float*)d_in[0];
    const float* Q = (const float*)d_in[1];
    const int* Cmask = (const int*)d_in[2];
    const int* Qmask = (const int*)d_in[3];
    const float* w  = (const float*)d_in[4];

    const size_t BNM = (size_t)BB * NN * MM;
    const size_t BMD = (size_t)BB * MM * DD;
    const size_t BND = (size_t)BB * NN * DD;
    const size_t BN  = (size_t)BB * NN;
    const size_t BM  = (size_t)BB * MM;

    _Float16* E  = (_Float16*)d_ws;            // 67.1 MB
    _Float16* Tt = E + BNM;                    // 16.8 MB  [b][d][m]
    _Float16* Qt = Tt + BMD;                   // 16.8 MB  [b][d][m]
    float* fbase = (float*)(Qt + BMD);
    float* c1   = fbase;
    float* q2   = c1 + BN;
    float* rsum = q2 + BM;
    float* csum = rsum + BN;

    // Scratch stashed in d_out: Ct in the outA region, Et in the outB region.
    // Both are fully consumed by k_T before k_AB overwrites d_out.
    _Float16* Ct = (_Float16*)d_out;                    // 67.1 MB <= 134 MB outA
    _Float16* Et = (_Float16*)((float*)d_out + BND);    // 67.1 MB <= 134 MB outB

    hipMemsetAsync(rsum, 0, (BN + BM) * sizeof(float), stream);

    k_dots<<<(int)((BN + BM) / 4), 256, 0, stream>>>(C, Q, w, c1, q2);
    k_qt<<<BB * 64, 256, 0, stream>>>(Q, Qmask, Qt);
    k_ct<<<BB * 256, 256, 0, stream>>>(C, Ct);
    k_sgemm<<<2048, 256, 0, stream>>>(C, Q, w, Cmask, Qmask, c1, q2, E, rsum, csum);
    k_te<<<BB * 256, 256, 0, stream>>>(E, Cmask, Et);
    k_T<<<512, 256, 0, stream>>>(Ct, Et, csum, Qmask, Tt);
    k_AB<<<2048, 256, 0, stream>>>(E, Qt, Tt, rsum,
                                   (float*)d_out, (float*)d_out + BND);
}